// Round 9
// baseline (246.087 us; speedup 1.0000x reference)
//
#include <hip/hip_runtime.h>

#define NRES 64
#define GRID_CELLS (NRES * NRES * NRES)
#define SLABZ 4
#define NSLABS 16
#define G_CHUNKS 32
#define TILE_CELLS (NRES * NRES * SLABZ)   // 16384
#define TPB 1024
#define CBLK 512                 // count blocks
#define FBLK 64                  // fill blocks (CBLK/FBLK = 8 regroup)
#define NBINS 2048               // (by%32)*64 + bz, class-major
#define MAXC 32
#define FXS 4194304.0f           // 2^22 fixed-point scale
#define INV_FXS (1.0f / 4194304.0f)
#define QS 2097152.0f            // 64 * 32768 position quantizer
typedef unsigned long long u64;
typedef unsigned u32;
typedef unsigned short u16;

// ws layout (main path):
//   blockCounts u16[NBINS*CBLK] @ 0          (2 MB)
//   scannedF    u16[NBINS*FBLK] @ 2 MB       (256 KB)
//   binTotals   u32[NBINS]      @ 2,359,296
//   binBases    u32[NBINS+1]    @ 2,367,488
//   bins        u64[2n]         @ 4 MB       (64 MB)
//   partial     int[512*16384]  @ 68 MB      (32 MB)
// total ~100.0 MB (<= round-8's proven 104,923,136 B)

__device__ __forceinline__ u32 quantc(float v) {
    return (u32)(v * QS + 0.5f);
}
__device__ __forceinline__ int cell_from_q(u32 q) {
    float s = (float)q * (1.0f / 32768.0f);
    int c = (int)(s - 0.5f);          // coords >= 3.2 so trunc == floor
    return min(max(c, 0), 63);
}

__global__ __launch_bounds__(TPB)
void count_kernel(const float* __restrict__ x, const float* __restrict__ xr,
                  int n, u16* __restrict__ blockCounts) {
    __shared__ u32 h[NBINS];
    for (int i = threadIdx.x; i < NBINS; i += TPB) h[i] = 0;
    __syncthreads();
    const int Q = n >> 2;
    const int GQ = 2 * Q;
    const int per = (GQ + CBLK - 1) / CBLK;
    const int g0 = blockIdx.x * per;
    const int g1 = min(GQ, g0 + per);
    for (int g = g0 + (int)threadIdx.x; g < g1; g += TPB) {
        const float* __restrict__ p = (g < Q) ? (x + 12 * (size_t)g)
                                              : (xr + 12 * (size_t)(g - Q));
        float4 a = ((const float4*)p)[0];
        float4 b = ((const float4*)p)[1];
        float4 c = ((const float4*)p)[2];
        float py[4] = {a.y, b.x, b.w, c.z};
        float pz[4] = {a.z, b.y, c.x, c.w};
#pragma unroll
        for (int q = 0; q < 4; ++q) {
            int by = cell_from_q(quantc(py[q]));
            int bz = cell_from_q(quantc(pz[q]));
            atomicAdd(&h[(by & 31) * 64 + bz], 1u);
        }
    }
    __syncthreads();
    for (int b = threadIdx.x; b < NBINS; b += TPB)
        blockCounts[b * CBLK + blockIdx.x] = (u16)h[b];
}

// one block per bin: scan 512 count-block values, emit every-8th exclusive
// prefix (= fill-block base within bin) and the bin total.
__global__ __launch_bounds__(CBLK)
void scanA_kernel(const u16* __restrict__ blockCounts,
                  u16* __restrict__ scannedF, u32* __restrict__ binTotals) {
    __shared__ u32 s[CBLK];
    const int b = blockIdx.x, t = threadIdx.x;
    u32 v = blockCounts[b * CBLK + t];
    s[t] = v;
    __syncthreads();
    for (int off = 1; off < CBLK; off <<= 1) {
        u32 add = (t >= off) ? s[t - off] : 0u;
        __syncthreads();
        s[t] += add;
        __syncthreads();
    }
    if ((t & 7) == 0) scannedF[b * FBLK + (t >> 3)] = (u16)(s[t] - v);
    if (t == CBLK - 1) binTotals[b] = s[t];
}

__global__ __launch_bounds__(1024)
void scanB_kernel(const u32* __restrict__ binTotals, u32* __restrict__ binBases) {
    __shared__ u32 s[NBINS];
    const int t = threadIdx.x;
    u32 v0 = binTotals[t];
    u32 v1 = binTotals[t + 1024];
    s[t] = v0; s[t + 1024] = v1;
    __syncthreads();
    for (int off = 1; off < NBINS; off <<= 1) {
        u32 a0 = (t >= off) ? s[t - off] : 0u;
        u32 a1 = (t + 1024 >= off) ? s[t + 1024 - off] : 0u;
        __syncthreads();
        s[t] += a0; s[t + 1024] += a1;
        __syncthreads();
    }
    binBases[t] = s[t] - v0;
    binBases[t + 1024] = s[t + 1024] - v1;
    if (t == 1023) binBases[NBINS] = s[NBINS - 1];
}

__global__ __launch_bounds__(TPB)
void fill_kernel(const float* __restrict__ x, const float* __restrict__ xr,
                 int n, const u16* __restrict__ scannedF,
                 const u32* __restrict__ binBases, u64* __restrict__ bins) {
    __shared__ u32 cur[NBINS];
    for (int b = threadIdx.x; b < NBINS; b += TPB)
        cur[b] = binBases[b] + (u32)scannedF[b * FBLK + blockIdx.x];
    __syncthreads();
    const int Q = n >> 2;
    const int GQ = 2 * Q;
    const int per = ((GQ + CBLK - 1) / CBLK) * 8;    // 8 count-blocks per fill-block
    const int g0 = blockIdx.x * per;
    const int g1 = min(GQ, g0 + per);
    const u32 cap = (u32)(2 * n);
#pragma unroll 2
    for (int g = g0 + (int)threadIdx.x; g < g1; g += TPB) {
        int inx = (g < Q);
        const float* __restrict__ p = inx ? (x + 12 * (size_t)g)
                                          : (xr + 12 * (size_t)(g - Q));
        float4 a = ((const float4*)p)[0];
        float4 b = ((const float4*)p)[1];
        float4 c = ((const float4*)p)[2];
        u64 sgn = inx ? 0ull : (1ull << 63);
        float px[4] = {a.x, a.w, b.z, c.y};
        float py[4] = {a.y, b.x, b.w, c.z};
        float pz[4] = {a.z, b.y, c.x, c.w};
#pragma unroll
        for (int q = 0; q < 4; ++q) {
            u32 xq = quantc(px[q]);
            u32 yq = quantc(py[q]);
            u32 zq = quantc(pz[q]);
            u64 ent = (u64)xq | ((u64)yq << 21) | ((u64)zq << 42) | sgn;
            int by = cell_from_q(yq);
            int bz = cell_from_q(zq);
            int bin = (by & 31) * 64 + bz;
            u32 slot = atomicAdd(&cur[bin], 1u);
            if (slot < cap) bins[slot] = ent;
        }
    }
}

// tile layout: idx = zl*4096 + bx*64 + by  -> bank = (by + j2) % 32.
// Lane l owns y-class c = l&31 (by%32 == c), lanes c and c+32 pair up:
// every atomic instruction hits each bank with exactly 2 lanes -> conflict-free.
__global__ __launch_bounds__(TPB)
void bin_scatter_kernel(const u64* __restrict__ bins,
                        const u32* __restrict__ binBases,
                        int* __restrict__ partial) {
    __shared__ int tile[TILE_CELLS];   // 64 KB fixed-point accumulators
    const int slab  = blockIdx.x / G_CHUNKS;
    const int chunk = blockIdx.x - slab * G_CHUNKS;
    const int z0 = slab * SLABZ;

    for (int i = threadIdx.x; i < TILE_CELLS / 4; i += TPB)
        reinterpret_cast<int4*>(tile)[i] = make_int4(0, 0, 0, 0);
    __syncthreads();

    const int lane = threadIdx.x & 63;
    const int wid  = threadIdx.x >> 6;      // 0..15
    const int c    = lane & 31;             // y-class
    const int sub  = lane >> 5;             // 0/1

    int zb1 = 4 * slab - 2; if (zb1 < 0) zb1 = 0;
    int zb2 = 4 * slab + 4; if (zb2 > 64) zb2 = 64;
    u32 lo = binBases[c * 64 + zb1];
    u32 hi = binBases[c * 64 + zb2];
    u32 cnt = hi - lo;
    u32 per = (cnt + (u32)G_CHUNKS - 1u) / (u32)G_CHUNKS;
    u32 start = lo + (u32)chunk * per;
    u32 end = start + per;
    if (end > hi) end = hi;
    u32 stream = (u32)(wid * 2 + sub);      // 0..31

    for (u32 e = start + stream; e < end; e += 32) {
        u64 v = bins[e];
        float xs = (float)(u32)(v & 0x1FFFFFu) * (1.0f / 32768.0f);
        float ys = (float)(u32)((v >> 21) & 0x1FFFFFu) * (1.0f / 32768.0f);
        float zs = (float)(u32)((v >> 42) & 0x1FFFFFu) * (1.0f / 32768.0f);
        float sgn = (v >> 63) ? -1.0f : 1.0f;

        int bx = (int)(xs - 0.5f);
        int by = (int)(ys - 0.5f);
        int bz = (int)(zs - 0.5f);
        float fx = xs - (float)bx, fy = ys - (float)by, fz = zs - (float)bz;

        float wx0 = 0.5f * (1.5f - fx) * (1.5f - fx);
        float wx1 = 0.75f - (fx - 1.0f) * (fx - 1.0f);
        float wx2 = 0.5f * (fx - 0.5f) * (fx - 0.5f);
        float wy0 = 0.5f * (1.5f - fy) * (1.5f - fy);
        float wy1 = 0.75f - (fy - 1.0f) * (fy - 1.0f);
        float wy2 = 0.5f * (fy - 0.5f) * (fy - 0.5f);
        float wzv[3];
        wzv[0] = 0.5f * (1.5f - fz) * (1.5f - fz);
        wzv[1] = 0.75f - (fz - 1.0f) * (fz - 1.0f);
        wzv[2] = 0.5f * (fz - 0.5f) * (fz - 0.5f);

        float wxy[9];
        wxy[0] = sgn * wx0 * wy0; wxy[1] = sgn * wx0 * wy1; wxy[2] = sgn * wx0 * wy2;
        wxy[3] = sgn * wx1 * wy0; wxy[4] = sgn * wx1 * wy1; wxy[5] = sgn * wx1 * wy2;
        wxy[6] = sgn * wx2 * wy0; wxy[7] = sgn * wx2 * wy1; wxy[8] = sgn * wx2 * wy2;

        int basexy = bx * 64 + by;
        int zlo = bz - z0;
#pragma unroll
        for (int k = 0; k < 3; ++k) {
            int zl = zlo + k;
            if ((u32)zl < (u32)SLABZ) {
                float wzS = wzv[k] * FXS;
                int a = zl * 4096 + basexy;
#pragma unroll
                for (int i2 = 0; i2 < 3; ++i2)
#pragma unroll
                    for (int j2 = 0; j2 < 3; ++j2)
                        atomicAdd(&tile[a + i2 * 64 + j2],
                                  __float2int_rn(wxy[i2 * 3 + j2] * wzS));
            }
        }
    }
    __syncthreads();

    int* __restrict__ dst = partial + (size_t)blockIdx.x * TILE_CELLS;
    for (int i = threadIdx.x; i < TILE_CELLS / 4; i += TPB)
        reinterpret_cast<int4*>(dst)[i] = reinterpret_cast<const int4*>(tile)[i];
}

__global__ void int_reduce_kernel(const int* __restrict__ partial,
                                  float* __restrict__ out) {
    int tid = blockIdx.x * blockDim.x + threadIdx.x;   // 0 .. 262143
    int s  = tid >> 14;          // slab
    int ti = tid & 16383;        // tile cell
    const int* __restrict__ p = partial + ((size_t)s * G_CHUNKS) * TILE_CELLS + ti;
    int sum = 0;
#pragma unroll 8
    for (int g = 0; g < G_CHUNKS; ++g) sum += p[(size_t)g * TILE_CELLS];
    float v = fabsf((float)sum) * INV_FXS;
#pragma unroll
    for (int off = 32; off > 0; off >>= 1) v += __shfl_down(v, off, 64);
    __shared__ float wsum[4];
    int lane = threadIdx.x & 63, wid = threadIdx.x >> 6;
    if (lane == 0) wsum[wid] = v;
    __syncthreads();
    if (threadIdx.x == 0) atomicAdd(out, wsum[0] + wsum[1] + wsum[2] + wsum[3]);
}

// ---------------- fallback path (round-2 kernels, verified correct) --------

__global__ __launch_bounds__(TPB)
void slab_scatter_kernel(const float* __restrict__ x,
                         const float* __restrict__ xr,
                         int n, int C, float* __restrict__ partial) {
    __shared__ float tile[TILE_CELLS];
    const int slab  = blockIdx.x / C;
    const int chunk = blockIdx.x - slab * C;
    const int z0 = slab * SLABZ;

    for (int i = threadIdx.x; i < TILE_CELLS; i += TPB) tile[i] = 0.0f;
    __syncthreads();

    const int per = (n + C - 1) / C;
    const int p0 = chunk * per;
    const int p1 = min(n, p0 + per);

    for (int f = 0; f < 2; ++f) {
        const float* __restrict__ p = f ? xr : x;
        const float sgn = f ? -1.0f : 1.0f;
        for (int i = p0 + (int)threadIdx.x; i < p1; i += TPB) {
            float zs = p[3 * i + 2] * 64.0f;
            int bz = (int)floorf(zs - 0.5f);
            int zlo = bz - z0;
            if (zlo > SLABZ - 1 || zlo + 2 < 0) continue;

            float xs = p[3 * i + 0] * 64.0f;
            float ys = p[3 * i + 1] * 64.0f;
            int bx = (int)floorf(xs - 0.5f);
            int by = (int)floorf(ys - 0.5f);
            float fx = xs - (float)bx, fy = ys - (float)by, fz = zs - (float)bz;

            float wx0 = 0.5f * (1.5f - fx) * (1.5f - fx);
            float wx1 = 0.75f - (fx - 1.0f) * (fx - 1.0f);
            float wx2 = 0.5f * (fx - 0.5f) * (fx - 0.5f);
            float wy0 = 0.5f * (1.5f - fy) * (1.5f - fy);
            float wy1 = 0.75f - (fy - 1.0f) * (fy - 1.0f);
            float wy2 = 0.5f * (fy - 0.5f) * (fy - 0.5f);
            float wzv[3];
            wzv[0] = 0.5f * (1.5f - fz) * (1.5f - fz);
            wzv[1] = 0.75f - (fz - 1.0f) * (fz - 1.0f);
            wzv[2] = 0.5f * (fz - 0.5f) * (fz - 0.5f);

            float wxy[9];
            wxy[0] = sgn * wx0 * wy0; wxy[1] = sgn * wx0 * wy1; wxy[2] = sgn * wx0 * wy2;
            wxy[3] = sgn * wx1 * wy0; wxy[4] = sgn * wx1 * wy1; wxy[5] = sgn * wx1 * wy2;
            wxy[6] = sgn * wx2 * wy0; wxy[7] = sgn * wx2 * wy1; wxy[8] = sgn * wx2 * wy2;

            int base = (bx * 64 + by) * 4;
#pragma unroll
            for (int k = 0; k < 3; ++k) {
                int zl = zlo + k;
                if (zl < 0 || zl >= SLABZ) continue;
                float wzk = wzv[k];
                int a = base + zl;
#pragma unroll
                for (int i2 = 0; i2 < 3; ++i2)
#pragma unroll
                    for (int j2 = 0; j2 < 3; ++j2)
                        atomicAdd(&tile[a + i2 * 256 + j2 * 4], wxy[i2 * 3 + j2] * wzk);
            }
        }
    }
    __syncthreads();

    float* __restrict__ dst = partial + (size_t)chunk * GRID_CELLS;
    for (int t = threadIdx.x; t < NRES * NRES; t += TPB) {
        float4 v = *reinterpret_cast<const float4*>(&tile[t * 4]);
        *reinterpret_cast<float4*>(&dst[t * 64 + z0]) = v;
    }
}

__global__ void reduce_kernel(const float* __restrict__ partial, int C,
                              float* __restrict__ out) {
    int cell = blockIdx.x * blockDim.x + threadIdx.x;
    float s = 0.0f;
    for (int c = 0; c < C; ++c) s += partial[(size_t)c * GRID_CELLS + cell];
    s = fabsf(s);
#pragma unroll
    for (int off = 32; off > 0; off >>= 1) s += __shfl_down(s, off, 64);
    __shared__ float wsum[4];
    int lane = threadIdx.x & 63, wid = threadIdx.x >> 6;
    if (lane == 0) wsum[wid] = s;
    __syncthreads();
    if (threadIdx.x == 0) atomicAdd(out, wsum[0] + wsum[1] + wsum[2] + wsum[3]);
}

extern "C" void kernel_launch(void* const* d_in, const int* in_sizes, int n_in,
                              void* d_out, int out_size, void* d_ws, size_t ws_size,
                              hipStream_t stream) {
    const float* x  = (const float*)d_in[0];
    const float* xr = (const float*)d_in[1];
    float* out = (float*)d_out;
    char* ws = (char*)d_ws;

    int n = in_sizes[0] / 3;  // 4,000,000

    const size_t OFF_COUNTS = 0;                                    // 2 MB
    const size_t OFF_SCANF  = (size_t)NBINS * CBLK * 2;             // 2 MB
    const size_t OFF_TOTALS = OFF_SCANF + (size_t)NBINS * FBLK * 2; // 2,359,296
    const size_t OFF_BASES  = OFF_TOTALS + NBINS * 4;               // 2,367,488
    const size_t OFF_BINS   = 4 * 1024 * 1024;                      // 4 MB
    const size_t binsBytes  = (size_t)(2 * n) * sizeof(u64);        // 64 MB
    const size_t OFF_PART   = OFF_BINS + binsBytes;
    const size_t partBytes  = (size_t)NSLABS * G_CHUNKS * TILE_CELLS * 4; // 32 MB
    const size_t gridBytes  = (size_t)GRID_CELLS * sizeof(float);

    hipMemsetAsync(out, 0, sizeof(float), stream);

    if ((n & 3) == 0 && ws_size >= OFF_PART + partBytes) {
        u16* blockCounts = (u16*)(ws + OFF_COUNTS);
        u16* scannedF    = (u16*)(ws + OFF_SCANF);
        u32* binTotals   = (u32*)(ws + OFF_TOTALS);
        u32* binBases    = (u32*)(ws + OFF_BASES);
        u64* bins        = (u64*)(ws + OFF_BINS);
        int* partial     = (int*)(ws + OFF_PART);

        count_kernel<<<CBLK, TPB, 0, stream>>>(x, xr, n, blockCounts);
        scanA_kernel<<<NBINS, CBLK, 0, stream>>>(blockCounts, scannedF, binTotals);
        scanB_kernel<<<1, 1024, 0, stream>>>(binTotals, binBases);
        fill_kernel<<<FBLK, TPB, 0, stream>>>(x, xr, n, scannedF, binBases, bins);
        bin_scatter_kernel<<<NSLABS * G_CHUNKS, TPB, 0, stream>>>(bins, binBases, partial);
        int_reduce_kernel<<<GRID_CELLS / 256, 256, 0, stream>>>(partial, out);
    } else {
        float* partial = (float*)ws;
        int C = (int)(ws_size / gridBytes);
        if (C > MAXC) C = MAXC;
        if (C < 1) C = 1;
        slab_scatter_kernel<<<NSLABS * C, TPB, 0, stream>>>(x, xr, n, C, partial);
        reduce_kernel<<<GRID_CELLS / 256, 256, 0, stream>>>(partial, C, out);
    }
}

// Round 10
// 136.209 us; speedup vs baseline: 1.8067x; 1.8067x over previous
//
#include <hip/hip_runtime.h>

#define NRES 64
#define GRID_CELLS (NRES * NRES * NRES)
#define TILE_CELLS 16384          // 4 z-planes x 64 x 64 (64 KB of int)
#define TPB 1024
#define NBLK 512                  // count/fill blocks
#define ZBINS 64
#define NSLABS2 32                // slabs own 2 bz values each
#define GC 16                     // chunks per slab -> 512 scatter blocks
#define MAXC 32
#define FXS 4194304.0f            // 2^22 fixed-point scale
#define INV_FXS (1.0f / 4194304.0f)
#define QS 2097152.0f             // 64 * 32768 position quantizer
typedef unsigned long long u64;
typedef unsigned u32;
typedef unsigned short u16;

// ws layout (main path), total 104,857,600 B (proven available):
//   counts  u16[64*512]   @ 0          (64 KB)
//   scanned u32[64*512]   @ 65,536     (128 KB)
//   totals  u32[64]       @ 196,608
//   bases   u32[65]       @ 196,864
//   bins    u64[2n=8M]    @ 4,194,304  (64 MB)
//   partial int[512*16384]@ 71,303,168 (32 MB)

__device__ __forceinline__ u32 quantc(float v) {
    return (u32)(v * QS + 0.5f);
}
__device__ __forceinline__ int cell_from_q(u32 q) {
    float s = (float)q * (1.0f / 32768.0f);
    int c = (int)(s - 0.5f);          // coords >= 3.2 so trunc == floor
    return min(max(c, 0), 63);
}

__global__ __launch_bounds__(TPB)
void count_kernel(const float* __restrict__ x, const float* __restrict__ xr,
                  int n, u16* __restrict__ blockCounts) {
    __shared__ u32 h[ZBINS];
    if (threadIdx.x < ZBINS) h[threadIdx.x] = 0;
    __syncthreads();
    const int Q = n >> 2;
    const int GQ = 2 * Q;
    for (int g = blockIdx.x * TPB + threadIdx.x; g < GQ; g += NBLK * TPB) {
        const float* __restrict__ p = (g < Q) ? (x + 12 * (size_t)g)
                                              : (xr + 12 * (size_t)(g - Q));
        float4 a = ((const float4*)p)[0];
        float4 b = ((const float4*)p)[1];
        float4 c = ((const float4*)p)[2];
        float pz[4] = {a.z, b.y, c.x, c.w};
#pragma unroll
        for (int q = 0; q < 4; ++q)
            atomicAdd(&h[cell_from_q(quantc(pz[q]))], 1u);
    }
    __syncthreads();
    if (threadIdx.x < ZBINS)
        blockCounts[threadIdx.x * NBLK + blockIdx.x] = (u16)h[threadIdx.x];
}

__global__ __launch_bounds__(NBLK)
void scanA_kernel(const u16* __restrict__ blockCounts,
                  u32* __restrict__ scanned, u32* __restrict__ totals) {
    __shared__ u32 s[NBLK];
    const int b = blockIdx.x, t = threadIdx.x;
    u32 v = blockCounts[b * NBLK + t];
    s[t] = v;
    __syncthreads();
    for (int off = 1; off < NBLK; off <<= 1) {
        u32 add = (t >= off) ? s[t - off] : 0u;
        __syncthreads();
        s[t] += add;
        __syncthreads();
    }
    scanned[b * NBLK + t] = s[t] - v;       // exclusive, u32 (totals ~125K)
    if (t == NBLK - 1) totals[b] = s[t];
}

__global__ void scanB_kernel(const u32* __restrict__ totals,
                             u32* __restrict__ bases) {
    if (threadIdx.x == 0 && blockIdx.x == 0) {
        u32 acc = 0;
        for (int i = 0; i < ZBINS; ++i) { bases[i] = acc; acc += totals[i]; }
        bases[ZBINS] = acc;
    }
}

__global__ __launch_bounds__(TPB)
void fill_kernel(const float* __restrict__ x, const float* __restrict__ xr,
                 int n, const u32* __restrict__ scanned,
                 const u32* __restrict__ bases, u64* __restrict__ bins) {
    __shared__ u32 cur[ZBINS];
    if (threadIdx.x < ZBINS)
        cur[threadIdx.x] = bases[threadIdx.x]
                         + scanned[threadIdx.x * NBLK + blockIdx.x];
    __syncthreads();
    const int Q = n >> 2;
    const int GQ = 2 * Q;
    const u32 cap = (u32)(2 * n);
    for (int g = blockIdx.x * TPB + threadIdx.x; g < GQ; g += NBLK * TPB) {
        int inx = (g < Q);
        const float* __restrict__ p = inx ? (x + 12 * (size_t)g)
                                          : (xr + 12 * (size_t)(g - Q));
        float4 a = ((const float4*)p)[0];
        float4 b = ((const float4*)p)[1];
        float4 c = ((const float4*)p)[2];
        u64 sgn = inx ? 0ull : (1ull << 63);
        float px[4] = {a.x, a.w, b.z, c.y};
        float py[4] = {a.y, b.x, b.w, c.z};
        float pz[4] = {a.z, b.y, c.x, c.w};
#pragma unroll
        for (int q = 0; q < 4; ++q) {
            u32 xq = quantc(px[q]);
            u32 yq = quantc(py[q]);
            u32 zq = quantc(pz[q]);
            u64 ent = (u64)xq | ((u64)yq << 21) | ((u64)zq << 42) | sgn;
            int bz = cell_from_q(zq);
            u32 slot = atomicAdd(&cur[bz], 1u);
            if (slot < cap) bins[slot] = ent;
        }
    }
}

// Single-visit scatter: slab s owns bz in {2s, 2s+1}; tile = 4 z-planes
// (global planes 2s .. 2s+3). Every entry writes zlo..zlo+2 with zlo in
// {0,1} -> always in-tile, unconditional 27-atomic body.
// tile layout: zl*4096 + bx*64 + by (bank = (by+j2)%32, z-plane-major).
__global__ __launch_bounds__(TPB)
void bin_scatter_kernel(const u64* __restrict__ bins,
                        const u32* __restrict__ bases,
                        int* __restrict__ partial) {
    __shared__ int tile[TILE_CELLS];   // 64 KB
    const int slab  = blockIdx.x / GC;
    const int chunk = blockIdx.x - slab * GC;

    for (int i = threadIdx.x; i < TILE_CELLS / 4; i += TPB)
        reinterpret_cast<int4*>(tile)[i] = make_int4(0, 0, 0, 0);
    __syncthreads();

    u32 lo = bases[2 * slab];
    u32 hi = bases[2 * slab + 2];
    u32 cnt = hi - lo;
    u32 per = (cnt + (u32)GC - 1u) / (u32)GC;
    u32 e0 = lo + (u32)chunk * per;
    u32 e1 = e0 + per;
    if (e1 > hi) e1 = hi;

    for (u32 e = e0 + threadIdx.x; e < e1; e += TPB) {
        u64 v = bins[e];
        float xs = (float)(u32)(v & 0x1FFFFFu) * (1.0f / 32768.0f);
        float ys = (float)(u32)((v >> 21) & 0x1FFFFFu) * (1.0f / 32768.0f);
        float zs = (float)(u32)((v >> 42) & 0x1FFFFFu) * (1.0f / 32768.0f);
        float sgn = (v >> 63) ? -1.0f : 1.0f;

        int bx = (int)(xs - 0.5f);
        int by = (int)(ys - 0.5f);
        int bz = (int)(zs - 0.5f);
        float fx = xs - (float)bx, fy = ys - (float)by, fz = zs - (float)bz;

        float wx0 = 0.5f * (1.5f - fx) * (1.5f - fx);
        float wx1 = 0.75f - (fx - 1.0f) * (fx - 1.0f);
        float wx2 = 0.5f * (fx - 0.5f) * (fx - 0.5f);
        float wy0 = 0.5f * (1.5f - fy) * (1.5f - fy);
        float wy1 = 0.75f - (fy - 1.0f) * (fy - 1.0f);
        float wy2 = 0.5f * (fy - 0.5f) * (fy - 0.5f);
        float wzv[3];
        wzv[0] = 0.5f * (1.5f - fz) * (1.5f - fz);
        wzv[1] = 0.75f - (fz - 1.0f) * (fz - 1.0f);
        wzv[2] = 0.5f * (fz - 0.5f) * (fz - 0.5f);

        float wxy[9];
        wxy[0] = sgn * wx0 * wy0; wxy[1] = sgn * wx0 * wy1; wxy[2] = sgn * wx0 * wy2;
        wxy[3] = sgn * wx1 * wy0; wxy[4] = sgn * wx1 * wy1; wxy[5] = sgn * wx1 * wy2;
        wxy[6] = sgn * wx2 * wy0; wxy[7] = sgn * wx2 * wy1; wxy[8] = sgn * wx2 * wy2;

        int basexy = bx * 64 + by;
        int zlo = bz - 2 * slab;            // 0 or 1, always valid
#pragma unroll
        for (int k = 0; k < 3; ++k) {
            float wzS = wzv[k] * FXS;
            int a = (zlo + k) * 4096 + basexy;
#pragma unroll
            for (int i2 = 0; i2 < 3; ++i2)
#pragma unroll
                for (int j2 = 0; j2 < 3; ++j2)
                    atomicAdd(&tile[a + i2 * 64 + j2],
                              __float2int_rn(wxy[i2 * 3 + j2] * wzS));
        }
    }
    __syncthreads();

    int* __restrict__ dst = partial + (size_t)blockIdx.x * TILE_CELLS;
    for (int i = threadIdx.x; i < TILE_CELLS / 4; i += TPB)
        reinterpret_cast<int4*>(dst)[i] = reinterpret_cast<const int4*>(tile)[i];
}

// Each cell z gets contributions from slab s0=z>>1 (plane z&1) and slab
// s0-1 (plane (z&1)+2), each replicated over GC chunks.
__global__ void int_reduce_kernel(const int* __restrict__ partial,
                                  float* __restrict__ out) {
    int tid = blockIdx.x * blockDim.x + threadIdx.x;   // 0 .. 262143
    int z  = tid >> 12;          // 0..63
    int xy = tid & 4095;
    int s0 = z >> 1, zl0 = z & 1;
    int sum = 0;
    const int* __restrict__ p0 =
        partial + (size_t)(s0 * GC) * TILE_CELLS + zl0 * 4096 + xy;
#pragma unroll 8
    for (int g = 0; g < GC; ++g) sum += p0[(size_t)g * TILE_CELLS];
    if (s0 > 0) {
        const int* __restrict__ p1 =
            partial + (size_t)((s0 - 1) * GC) * TILE_CELLS + (zl0 + 2) * 4096 + xy;
#pragma unroll 8
        for (int g = 0; g < GC; ++g) sum += p1[(size_t)g * TILE_CELLS];
    }
    float v = fabsf((float)sum) * INV_FXS;
#pragma unroll
    for (int off = 32; off > 0; off >>= 1) v += __shfl_down(v, off, 64);
    __shared__ float wsum[4];
    int lane = threadIdx.x & 63, wid = threadIdx.x >> 6;
    if (lane == 0) wsum[wid] = v;
    __syncthreads();
    if (threadIdx.x == 0) atomicAdd(out, wsum[0] + wsum[1] + wsum[2] + wsum[3]);
}

// ---------------- fallback path (round-2 kernels, verified correct) --------

__global__ __launch_bounds__(TPB)
void slab_scatter_kernel(const float* __restrict__ x,
                         const float* __restrict__ xr,
                         int n, int C, float* __restrict__ partial) {
    __shared__ float tile[TILE_CELLS];
    const int slab  = blockIdx.x / C;
    const int chunk = blockIdx.x - slab * C;
    const int z0 = slab * 4;

    for (int i = threadIdx.x; i < TILE_CELLS; i += TPB) tile[i] = 0.0f;
    __syncthreads();

    const int per = (n + C - 1) / C;
    const int p0 = chunk * per;
    const int p1 = min(n, p0 + per);

    for (int f = 0; f < 2; ++f) {
        const float* __restrict__ p = f ? xr : x;
        const float sgn = f ? -1.0f : 1.0f;
        for (int i = p0 + (int)threadIdx.x; i < p1; i += TPB) {
            float zs = p[3 * i + 2] * 64.0f;
            int bz = (int)floorf(zs - 0.5f);
            int zlo = bz - z0;
            if (zlo > 3 || zlo + 2 < 0) continue;

            float xs = p[3 * i + 0] * 64.0f;
            float ys = p[3 * i + 1] * 64.0f;
            int bx = (int)floorf(xs - 0.5f);
            int by = (int)floorf(ys - 0.5f);
            float fx = xs - (float)bx, fy = ys - (float)by, fz = zs - (float)bz;

            float wx0 = 0.5f * (1.5f - fx) * (1.5f - fx);
            float wx1 = 0.75f - (fx - 1.0f) * (fx - 1.0f);
            float wx2 = 0.5f * (fx - 0.5f) * (fx - 0.5f);
            float wy0 = 0.5f * (1.5f - fy) * (1.5f - fy);
            float wy1 = 0.75f - (fy - 1.0f) * (fy - 1.0f);
            float wy2 = 0.5f * (fy - 0.5f) * (fy - 0.5f);
            float wzv[3];
            wzv[0] = 0.5f * (1.5f - fz) * (1.5f - fz);
            wzv[1] = 0.75f - (fz - 1.0f) * (fz - 1.0f);
            wzv[2] = 0.5f * (fz - 0.5f) * (fz - 0.5f);

            float wxy[9];
            wxy[0] = sgn * wx0 * wy0; wxy[1] = sgn * wx0 * wy1; wxy[2] = sgn * wx0 * wy2;
            wxy[3] = sgn * wx1 * wy0; wxy[4] = sgn * wx1 * wy1; wxy[5] = sgn * wx1 * wy2;
            wxy[6] = sgn * wx2 * wy0; wxy[7] = sgn * wx2 * wy1; wxy[8] = sgn * wx2 * wy2;

            int base = (bx * 64 + by) * 4;
#pragma unroll
            for (int k = 0; k < 3; ++k) {
                int zl = zlo + k;
                if (zl < 0 || zl >= 4) continue;
                float wzk = wzv[k];
                int a = base + zl;
#pragma unroll
                for (int i2 = 0; i2 < 3; ++i2)
#pragma unroll
                    for (int j2 = 0; j2 < 3; ++j2)
                        atomicAdd(&tile[a + i2 * 256 + j2 * 4], wxy[i2 * 3 + j2] * wzk);
            }
        }
    }
    __syncthreads();

    float* __restrict__ dst = partial + (size_t)chunk * GRID_CELLS;
    for (int t = threadIdx.x; t < NRES * NRES; t += TPB) {
        float4 v = *reinterpret_cast<const float4*>(&tile[t * 4]);
        *reinterpret_cast<float4*>(&dst[t * 64 + z0]) = v;
    }
}

__global__ void reduce_kernel(const float* __restrict__ partial, int C,
                              float* __restrict__ out) {
    int cell = blockIdx.x * blockDim.x + threadIdx.x;
    float s = 0.0f;
    for (int c = 0; c < C; ++c) s += partial[(size_t)c * GRID_CELLS + cell];
    s = fabsf(s);
#pragma unroll
    for (int off = 32; off > 0; off >>= 1) s += __shfl_down(s, off, 64);
    __shared__ float wsum[4];
    int lane = threadIdx.x & 63, wid = threadIdx.x >> 6;
    if (lane == 0) wsum[wid] = s;
    __syncthreads();
    if (threadIdx.x == 0) atomicAdd(out, wsum[0] + wsum[1] + wsum[2] + wsum[3]);
}

extern "C" void kernel_launch(void* const* d_in, const int* in_sizes, int n_in,
                              void* d_out, int out_size, void* d_ws, size_t ws_size,
                              hipStream_t stream) {
    const float* x  = (const float*)d_in[0];
    const float* xr = (const float*)d_in[1];
    float* out = (float*)d_out;
    char* ws = (char*)d_ws;

    int n = in_sizes[0] / 3;  // 4,000,000

    const size_t OFF_COUNTS = 0;                                   // 64 KB
    const size_t OFF_SCAN   = 65536;                               // 128 KB
    const size_t OFF_TOTALS = 196608;
    const size_t OFF_BASES  = 196864;
    const size_t OFF_BINS   = 4 * 1024 * 1024;                     // 64 MB
    const size_t binsBytes  = (size_t)(2 * n) * sizeof(u64);
    const size_t OFF_PART   = OFF_BINS + binsBytes;                // 71,303,168
    const size_t partBytes  = (size_t)NSLABS2 * GC * TILE_CELLS * 4; // 32 MB
    const size_t gridBytes  = (size_t)GRID_CELLS * sizeof(float);

    hipMemsetAsync(out, 0, sizeof(float), stream);

    if ((n & 3) == 0 && ws_size >= OFF_PART + partBytes) {
        u16* blockCounts = (u16*)(ws + OFF_COUNTS);
        u32* scanned     = (u32*)(ws + OFF_SCAN);
        u32* totals      = (u32*)(ws + OFF_TOTALS);
        u32* bases       = (u32*)(ws + OFF_BASES);
        u64* bins        = (u64*)(ws + OFF_BINS);
        int* partial     = (int*)(ws + OFF_PART);

        count_kernel<<<NBLK, TPB, 0, stream>>>(x, xr, n, blockCounts);
        scanA_kernel<<<ZBINS, NBLK, 0, stream>>>(blockCounts, scanned, totals);
        scanB_kernel<<<1, 64, 0, stream>>>(totals, bases);
        fill_kernel<<<NBLK, TPB, 0, stream>>>(x, xr, n, scanned, bases, bins);
        bin_scatter_kernel<<<NSLABS2 * GC, TPB, 0, stream>>>(bins, bases, partial);
        int_reduce_kernel<<<GRID_CELLS / 256, 256, 0, stream>>>(partial, out);
    } else {
        float* partial = (float*)ws;
        int C = (int)(ws_size / gridBytes);
        if (C > MAXC) C = MAXC;
        if (C < 1) C = 1;
        slab_scatter_kernel<<<16 * C, TPB, 0, stream>>>(x, xr, n, C, partial);
        reduce_kernel<<<GRID_CELLS / 256, 256, 0, stream>>>(partial, C, out);
    }
}